// Round 8
// baseline (438.068 us; speedup 1.0000x reference)
//
#include <hip/hip_runtime.h>
#include <hip/hip_bf16.h>

#define B_ 8
#define S_ 1024
#define D_ 512
#define H_ 8
#define DK_ 64
#define HD_ 4096   // H_*D_

typedef __attribute__((ext_vector_type(8))) short bf16x8;
typedef __attribute__((ext_vector_type(4))) float f32x4;

static __device__ __forceinline__ unsigned short f2bf(float f) {
    unsigned u = __float_as_uint(f);
    unsigned r = (u + 0x7fffu + ((u >> 16) & 1u)) >> 16;  // RNE
    return (unsigned short)r;
}

// async global(16B/lane) -> LDS (wave-uniform base + lane*16)
static __device__ __forceinline__ void gload16(const unsigned short* g, unsigned short* l) {
    __builtin_amdgcn_global_load_lds(
        (const __attribute__((address_space(1))) void*)g,
        (__attribute__((address_space(3))) void*)l, 16, 0, 0);
}

// P_lds index: [ql][k] with 16B-slot XOR swizzle (slot ^= ql&7). Units: shorts.
static __device__ __forceinline__ int plidx(int ql, int k) {
    return ql * 1024 + ((((k >> 3) ^ (ql & 7))) << 3) + (k & 7);
}

// ---------------------------------------------------------------------------
// K0: generic f32 -> bf16 convert, 4 elems/thread. grid = count/1024.
// ---------------------------------------------------------------------------
__global__ __launch_bounds__(256) void cvt_kernel(
    const float* __restrict__ src, unsigned short* __restrict__ dst)
{
    const size_t i = ((size_t)blockIdx.x * 256 + threadIdx.x) * 4;
    float4 v = *(const float4*)&src[i];
    ushort4 u = { f2bf(v.x), f2bf(v.y), f2bf(v.z), f2bf(v.w) };
    *(ushort4*)&dst[i] = u;
}

// ---------------------------------------------------------------------------
// K1: V transpose+convert: Vt[b][e][s] bf16 from V[b][s][e] f32.
// ---------------------------------------------------------------------------
__global__ __launch_bounds__(256) void vt_kernel(
    const float* __restrict__ V, unsigned short* __restrict__ Vt)
{
    __shared__ float tile[32][33];
    const int b = blockIdx.z, s0 = blockIdx.x * 32, e0 = blockIdx.y * 32;
    const int t = threadIdx.x;
    const int r = t >> 3, c4 = (t & 7) * 4;
    float4 v = *(const float4*)&V[((size_t)b * S_ + s0 + r) * D_ + e0 + c4];
    tile[r][c4 + 0] = v.x; tile[r][c4 + 1] = v.y;
    tile[r][c4 + 2] = v.z; tile[r][c4 + 3] = v.w;
    __syncthreads();
    ushort4 u;
    u.x = f2bf(tile[c4 + 0][r]); u.y = f2bf(tile[c4 + 1][r]);
    u.z = f2bf(tile[c4 + 2][r]); u.w = f2bf(tile[c4 + 3][r]);
    *(ushort4*)&Vt[((size_t)b * D_ + e0 + r) * S_ + s0 + c4] = u;
}

// ---------------------------------------------------------------------------
// K2: 128xTN-tile bf16 MFMA GEMM, BK=32, double-buffered LDS staged via
// global_load_lds (16B), source-side XOR slot swizzle. 256 thr (4 waves 2x2).
// C = A[M x K] @ Bw[512 x K]^T. grid = 64 * (512/TN), XCD-chunked swizzle.
// MODE 0: P[b][h][s][dk] = bf16((C + bias) * scale)   (QK projection)
// MODE 1: Y = C + bias + Vres (f32)                   (output projection)
// ---------------------------------------------------------------------------
template<int KDIM, int TN, int MODE>
__global__ __launch_bounds__(256) void gemm_t(
    const unsigned short* __restrict__ A, const unsigned short* __restrict__ Bw,
    const float* __restrict__ bias, const float* __restrict__ Vres,
    void* __restrict__ Out, float scale)
{
    constexpr int NB = 512 / TN;       // n-blocks per m-row
    constexpr int CF = TN / 32;        // col frags per wave
    const int o = blockIdx.x;
    const int cpx = gridDim.x / 8;
    const int nb = (o % 8) * cpx + o / 8;   // XCD-chunked bijection
    const int m0 = (nb / NB) * 128;
    const int n0 = (nb % NB) * TN;

    __shared__ __align__(16) unsigned short As[2][128 * 32];
    __shared__ __align__(16) unsigned short Bs[2][TN * 32];

    const int t = threadIdx.x;
    const int wave = t >> 6, lane = t & 63;
    const int wr = wave >> 1, wc = wave & 1;
    const int lr = lane & 15, g = lane >> 4;
    const int gx = (g ^ (lr & 3)) << 3;        // swizzled k-slot (shorts)

    f32x4 acc[4][CF];
    #pragma unroll
    for (int r = 0; r < 4; ++r)
        #pragma unroll
        for (int c = 0; c < CF; ++c) acc[r][c] = (f32x4){0.f, 0.f, 0.f, 0.f};

    const int sub = lane >> 2;                              // row within chunk
    const int cb  = (((lane & 3) ^ (sub & 3)) << 3);        // swizzled src col

    auto stage = [&](int buf, int k0) {
        #pragma unroll
        for (int s = 0; s < 2; ++s) {
            const int chunk = s * 4 + wave;
            const int row = chunk * 16 + sub;
            gload16(&A[(size_t)(m0 + row) * KDIM + k0 + cb], &As[buf][chunk * 512]);
        }
        #pragma unroll
        for (int s = 0; s < TN / 64; ++s) {
            const int chunk = s * 4 + wave;
            const int row = chunk * 16 + sub;
            gload16(&Bw[(size_t)(n0 + row) * KDIM + k0 + cb], &Bs[buf][chunk * 512]);
        }
    };
    auto compute = [&](int cur) {
        bf16x8 af[4], bfr[CF];
        #pragma unroll
        for (int r = 0; r < 4; ++r)
            af[r] = *(const bf16x8*)&As[cur][(wr * 64 + r * 16 + lr) * 32 + gx];
        #pragma unroll
        for (int c = 0; c < CF; ++c)
            bfr[c] = *(const bf16x8*)&Bs[cur][(wc * (TN / 2) + c * 16 + lr) * 32 + gx];
        #pragma unroll
        for (int c = 0; c < CF; ++c)
            #pragma unroll
            for (int r = 0; r < 4; ++r)
                acc[r][c] = __builtin_amdgcn_mfma_f32_16x16x32_bf16(af[r], bfr[c], acc[r][c], 0, 0, 0);
    };

    const int NT = KDIM / 32;
    stage(0, 0);
    __syncthreads();
    int cur = 0;
    for (int tt = 0; tt < NT - 1; ++tt) {
        stage(cur ^ 1, (tt + 1) * 32);   // issue next-tile loads first
        compute(cur);                    // MFMA hides the load latency
        __syncthreads();                 // drain + WAR protect
        cur ^= 1;
    }
    compute(cur);

    float bn[CF];
    #pragma unroll
    for (int c = 0; c < CF; ++c) bn[c] = bias[n0 + wc * (TN / 2) + c * 16 + lr];

    #pragma unroll
    for (int r = 0; r < 4; ++r) {
        #pragma unroll
        for (int c = 0; c < CF; ++c) {
            const int n = n0 + wc * (TN / 2) + c * 16 + lr;
            #pragma unroll
            for (int i = 0; i < 4; ++i) {
                const int m = m0 + wr * 64 + r * 16 + g * 4 + i;
                if constexpr (MODE == 0) {
                    const int srow = m & 1023, bb = m >> 10;
                    const int h = n >> 6, dk = n & 63;
                    ((unsigned short*)Out)[(((size_t)(bb * H_ + h)) * S_ + srow) * DK_ + dk] =
                        f2bf((acc[r][c][i] + bn[c]) * scale);
                } else {
                    const size_t oo = (size_t)m * D_ + n;
                    ((float*)Out)[oo] = acc[r][c][i] + bn[c] + Vres[oo];
                }
            }
        }
    }
}

// ---------------------------------------------------------------------------
// K3: FUSED attention, QBLK=32, 8 waves (512 thr), 2 blocks/CU (66 KB LDS).
// Swapped QK^T (per-wave k-window 128) -> reg softmax -> P bf16 swizzled LDS
// -> PV MFMA with attn f32 writes interleaved into the k-loop -> AV scatter.
// grid (32, 64).
// ---------------------------------------------------------------------------
__global__ __launch_bounds__(512, 4) void fused_attn(
    const unsigned short* __restrict__ Qbf,   // [B][H][S][64], pre-scaled 0.125
    const unsigned short* __restrict__ Kbf,   // [B][H][S][64]
    const unsigned short* __restrict__ Vt,    // [B][512][1024]
    float* __restrict__ attn,                 // [B][H][S][S]
    unsigned short* __restrict__ AV)          // [B*S][4096]
{
    const int bh = blockIdx.y;
    const int b = bh >> 3, h = bh & 7;
    const int q0 = blockIdx.x * 32;
    const unsigned short* Qb = Qbf + (size_t)bh * S_ * DK_;
    const unsigned short* Kb = Kbf + (size_t)bh * S_ * DK_;
    const unsigned short* Vb = Vt + (size_t)b * D_ * S_;
    float* outp = attn + ((size_t)bh << 20);

    __shared__ unsigned short PL[32 * 1024];   // 64 KB, swizzled [q][k] bf16
    __shared__ float redm[32][8];
    __shared__ float rowm[32];

    const int t = threadIdx.x;
    const int wave = t >> 6, lane = t & 63;
    const int wcol = wave * 128;    // QK: this wave's k-col window
    const int lr = lane & 15;
    const int g  = lane >> 4;       // 0..3

    // ---- QK^T (swapped): acc[r][c][i] = S[k = wcol+r*16+g*4+i][q = c*16+lr]
    f32x4 acc[8][2];
    #pragma unroll
    for (int r = 0; r < 8; ++r)
        #pragma unroll
        for (int c = 0; c < 2; ++c) acc[r][c] = (f32x4){0.f, 0.f, 0.f, 0.f};

    #pragma unroll
    for (int kk = 0; kk < 2; ++kk) {
        bf16x8 qf[2];   // Q fragments (B operand, cols = q-rows)
        #pragma unroll
        for (int c = 0; c < 2; ++c)
            qf[c] = *(const bf16x8*)&Qb[(size_t)(q0 + c * 16 + lr) * DK_ + kk * 32 + g * 8];
        #pragma unroll
        for (int half = 0; half < 2; ++half) {
            bf16x8 af[4];   // K fragments (A operand, rows = k-cols)
            #pragma unroll
            for (int r = 0; r < 4; ++r)
                af[r] = *(const bf16x8*)&Kb[(size_t)(wcol + (half * 4 + r) * 16 + lr) * DK_ + kk * 32 + g * 8];
            #pragma unroll
            for (int r = 0; r < 4; ++r)
                #pragma unroll
                for (int c = 0; c < 2; ++c)
                    acc[half * 4 + r][c] =
                        __builtin_amdgcn_mfma_f32_16x16x32_bf16(af[r], qf[c], acc[half * 4 + r][c], 0, 0, 0);
        }
    }

    // ---- softmax: wave-local max over this wave's 128-k window
    float mloc[2];
    #pragma unroll
    for (int c = 0; c < 2; ++c) {
        float m = acc[0][c][0];
        #pragma unroll
        for (int r = 0; r < 8; ++r)
            #pragma unroll
            for (int i = 0; i < 4; ++i) m = fmaxf(m, acc[r][c][i]);
        m = fmaxf(m, __shfl_xor(m, 16));
        m = fmaxf(m, __shfl_xor(m, 32));
        mloc[c] = m;
    }
    if (lane < 16) {
        #pragma unroll
        for (int c = 0; c < 2; ++c) redm[c * 16 + lane][wave] = mloc[c];
    }
    __syncthreads();
    if (t < 32) {
        float m = redm[t][0];
        #pragma unroll
        for (int w = 1; w < 8; ++w) m = fmaxf(m, redm[t][w]);
        rowm[t] = m;
    }
    __syncthreads();
    // ---- exp + wave-local sum
    float sloc[2];
    #pragma unroll
    for (int c = 0; c < 2; ++c) {
        const float m = rowm[c * 16 + lr];
        float s = 0.f;
        #pragma unroll
        for (int r = 0; r < 8; ++r)
            #pragma unroll
            for (int i = 0; i < 4; ++i) {
                float p = __expf(acc[r][c][i] - m);
                acc[r][c][i] = p;
                s += p;
            }
        s += __shfl_xor(s, 16);
        s += __shfl_xor(s, 32);
        sloc[c] = s;
    }
    __syncthreads();
    if (lane < 16) {
        #pragma unroll
        for (int c = 0; c < 2; ++c) redm[c * 16 + lane][wave] = sloc[c];
    }
    __syncthreads();
    if (t < 32) {
        float s = redm[t][0];
        #pragma unroll
        for (int w = 1; w < 8; ++w) s += redm[t][w];
        rowm[t] = 1.0f / s;
    }
    __syncthreads();

    // ---- normalize; pack P bf16 -> swizzled LDS
    #pragma unroll
    for (int c = 0; c < 2; ++c) {
        const int ql = c * 16 + lr;
        const float ri = rowm[ql];
        #pragma unroll
        for (int r = 0; r < 8; ++r) {
            f32x4 v = acc[r][c];
            v[0] *= ri; v[1] *= ri; v[2] *= ri; v[3] *= ri;
            const int k = wcol + r * 16 + g * 4;
            unsigned p01 = (unsigned)f2bf(v[0]) | ((unsigned)f2bf(v[1]) << 16);
            unsigned p23 = (unsigned)f2bf(v[2]) | ((unsigned)f2bf(v[3]) << 16);
            uint2 pk = { p01, p23 };
            *(uint2*)&PL[plidx(ql, k)] = pk;
        }
    }
    __syncthreads();

    // ---- PV with attn writes interleaved (store queue busy under MFMA).
    // Wave owns e in [wave*64, +64).
    const int we = wave * 64;
    f32x4 accv[2][4];
    #pragma unroll
    for (int r = 0; r < 2; ++r)
        #pragma unroll
        for (int c = 0; c < 4; ++c) accv[r][c] = (f32x4){0.f, 0.f, 0.f, 0.f};

    const int arow = t >> 4;          // 0..31 (attn write row)
    const int acol = (t & 15) * 4;    // 0..60 within 64-col round

    #pragma unroll 2
    for (int k0 = 0; k0 < S_; k0 += 32) {
        bf16x8 pa[2];
        #pragma unroll
        for (int r = 0; r < 2; ++r)
            pa[r] = *(const bf16x8*)&PL[plidx(r * 16 + lr, k0 + g * 8)];
        if ((k0 & 32) == 0) {
            // one 64-col round of the attn f32 write, from PL
            const int col = (k0 >> 6) * 64 + acol;
            uint2 u = *(const uint2*)&PL[plidx(arow, col)];
            float4 f;
            f.x = __uint_as_float((u.x & 0xffffu) << 16);
            f.y = __uint_as_float(u.x & 0xffff0000u);
            f.z = __uint_as_float((u.y & 0xffffu) << 16);
            f.w = __uint_as_float(u.y & 0xffff0000u);
            *(float4*)&outp[((size_t)(q0 + arow) << 10) + col] = f;
        }
        #pragma unroll
        for (int c = 0; c < 4; ++c) {
            const int e = we + c * 16 + lr;
            bf16x8 vf = *(const bf16x8*)&Vb[(size_t)e * S_ + k0 + g * 8];
            #pragma unroll
            for (int r = 0; r < 2; ++r)
                accv[r][c] = __builtin_amdgcn_mfma_f32_16x16x32_bf16(pa[r], vf, accv[r][c], 0, 0, 0);
        }
    }

    // ---- AV scatter store
    #pragma unroll
    for (int r = 0; r < 2; ++r) {
        #pragma unroll
        for (int c = 0; c < 4; ++c) {
            const int e = we + c * 16 + lr;
            #pragma unroll
            for (int i = 0; i < 4; ++i) {
                const int row = q0 + r * 16 + g * 4 + i;
                AV[((size_t)(b * S_ + row)) * HD_ + h * D_ + e] = f2bf(accv[r][c][i]);
            }
        }
    }
}

// ---------------------------------------------------------------------------
// K4: LayerNorm in place. grid 2048, block 256.
// ---------------------------------------------------------------------------
__global__ __launch_bounds__(256) void ln_kernel(
    float* __restrict__ Y, const float* __restrict__ gamma,
    const float* __restrict__ beta)
{
    const int lane = threadIdx.x & 63;
    const int wave = threadIdx.x >> 6;
    const size_t row = (size_t)blockIdx.x * 4 + wave;
    float* p = Y + row * D_;
    float4 v0 = *(float4*)&p[lane * 4];
    float4 v1 = *(float4*)&p[256 + lane * 4];
    float s = v0.x + v0.y + v0.z + v0.w + v1.x + v1.y + v1.z + v1.w;
    float q = v0.x * v0.x + v0.y * v0.y + v0.z * v0.z + v0.w * v0.w +
              v1.x * v1.x + v1.y * v1.y + v1.z * v1.z + v1.w * v1.w;
    #pragma unroll
    for (int m = 1; m < 64; m <<= 1) {
        s += __shfl_xor(s, m);
        q += __shfl_xor(q, m);
    }
    const float mu  = s * (1.f / 512.f);
    const float var = q * (1.f / 512.f) - mu * mu;
    const float r = rsqrtf(var + 1e-5f);
    const float4 g0 = *(const float4*)&gamma[lane * 4];
    const float4 g1 = *(const float4*)&gamma[256 + lane * 4];
    const float4 b0 = *(const float4*)&beta[lane * 4];
    const float4 b1 = *(const float4*)&beta[256 + lane * 4];
    v0.x = (v0.x - mu) * r * g0.x + b0.x;
    v0.y = (v0.y - mu) * r * g0.y + b0.y;
    v0.z = (v0.z - mu) * r * g0.z + b0.z;
    v0.w = (v0.w - mu) * r * g0.w + b0.w;
    v1.x = (v1.x - mu) * r * g1.x + b1.x;
    v1.y = (v1.y - mu) * r * g1.y + b1.y;
    v1.z = (v1.z - mu) * r * g1.z + b1.z;
    v1.w = (v1.w - mu) * r * g1.w + b1.w;
    *(float4*)&p[lane * 4] = v0;
    *(float4*)&p[256 + lane * 4] = v1;
}

// ---------------------------------------------------------------------------
extern "C" void kernel_launch(void* const* d_in, const int* in_sizes, int n_in,
                              void* d_out, int out_size, void* d_ws, size_t ws_size,
                              hipStream_t stream)
{
    const float* query = (const float*)d_in[0];
    const float* key   = (const float*)d_in[1];
    const float* value = (const float*)d_in[2];
    const float* Wq    = (const float*)d_in[3];
    const float* bq    = (const float*)d_in[4];
    const float* Wk    = (const float*)d_in[5];
    const float* bk    = (const float*)d_in[6];
    const float* Wo    = (const float*)d_in[7];
    const float* bo    = (const float*)d_in[8];
    const float* gamma = (const float*)d_in[9];
    const float* beta  = (const float*)d_in[10];

    float* out  = (float*)d_out;                       // [B,S,D] (16 MiB)
    float* attn = out + (size_t)B_ * S_ * D_;          // [B,H,S,S] (256 MiB)
    char*  attnB = (char*)attn;

    char* ws = (char*)d_ws;
    // ws (76 MB): AV [0,64) bf16 ; Vt [64,72) bf16 ; Wobf [72,76) bf16.
    unsigned short* AV   = (unsigned short*)ws;
    unsigned short* Vt   = (unsigned short*)(ws + ((size_t)64 << 20));
    unsigned short* Wobf = (unsigned short*)(ws + ((size_t)72 << 20));
    // Qbf/Kbf (8 MiB each) in the OUT region of d_out (dead before out-GEMM).
    unsigned short* Qbf  = (unsigned short*)d_out;
    unsigned short* Kbf  = (unsigned short*)d_out + ((size_t)4 << 20);  // shorts
    // bf16 copies of X and W live in the tail of the ATTN region — consumed
    // by the projections, which complete before fused_attn overwrites attn.
    unsigned short* Xq   = (unsigned short*)(attnB + ((size_t)200 << 20));
    unsigned short* Xk   = (unsigned short*)(attnB + ((size_t)210 << 20));
    unsigned short* Wqbf = (unsigned short*)(attnB + ((size_t)220 << 20));
    unsigned short* Wkbf = (unsigned short*)(attnB + ((size_t)221 << 20));

    cvt_kernel<<<4096, 256, 0, stream>>>(query, Xq);
    cvt_kernel<<<4096, 256, 0, stream>>>(key,   Xk);
    cvt_kernel<<<256,  256, 0, stream>>>(Wq, Wqbf);
    cvt_kernel<<<256,  256, 0, stream>>>(Wk, Wkbf);
    cvt_kernel<<<2048, 256, 0, stream>>>(Wo, Wobf);
    vt_kernel<<<dim3(32, 16, 8), 256, 0, stream>>>(value, Vt);
    gemm_t<512, 64, 0><<<512, 256, 0, stream>>>(Xq, Wqbf, bq, nullptr, (void*)Qbf, 0.125f);
    gemm_t<512, 64, 0><<<512, 256, 0, stream>>>(Xk, Wkbf, bk, nullptr, (void*)Kbf, 1.0f);
    fused_attn<<<dim3(32, 64), 512, 0, stream>>>(Qbf, Kbf, Vt, attn, AV);
    gemm_t<4096, 64, 1><<<512, 256, 0, stream>>>(AV, Wobf, bo, value, (void*)out, 0.f);
    ln_kernel<<<2048, 256, 0, stream>>>(out, gamma, beta);
}

// Round 10
// 349.057 us; speedup vs baseline: 1.2550x; 1.2550x over previous
//
#include <hip/hip_runtime.h>
#include <hip/hip_bf16.h>

#define B_ 8
#define S_ 1024
#define D_ 512
#define H_ 8
#define DK_ 64
#define HD_ 4096   // H_*D_

typedef __attribute__((ext_vector_type(8))) short bf16x8;
typedef __attribute__((ext_vector_type(4))) float f32x4;

static __device__ __forceinline__ unsigned short f2bf(float f) {
    unsigned u = __float_as_uint(f);
    unsigned r = (u + 0x7fffu + ((u >> 16) & 1u)) >> 16;  // RNE
    return (unsigned short)r;
}

// async global(16B/lane) -> LDS (wave-uniform base + lane*16)
static __device__ __forceinline__ void gload16(const unsigned short* g, unsigned short* l) {
    __builtin_amdgcn_global_load_lds(
        (const __attribute__((address_space(1))) void*)g,
        (__attribute__((address_space(3))) void*)l, 16, 0, 0);
}

// P_lds index: [ql][k] with 16B-slot XOR swizzle (slot ^= ql&7). Units: shorts.
static __device__ __forceinline__ int plidx(int ql, int k) {
    return ql * 1024 + ((((k >> 3) ^ (ql & 7))) << 3) + (k & 7);
}

// ---------------------------------------------------------------------------
// K0a: f32 -> bf16 convert. K0b: two-buffer variant (merged launches).
// ---------------------------------------------------------------------------
__global__ __launch_bounds__(256) void cvt_kernel(
    const float* __restrict__ src, unsigned short* __restrict__ dst)
{
    const size_t i = ((size_t)blockIdx.x * 256 + threadIdx.x) * 4;
    float4 v = *(const float4*)&src[i];
    ushort4 u = { f2bf(v.x), f2bf(v.y), f2bf(v.z), f2bf(v.w) };
    *(ushort4*)&dst[i] = u;
}

__global__ __launch_bounds__(256) void cvt2_kernel(
    const float* __restrict__ s0, unsigned short* __restrict__ d0,
    const float* __restrict__ s1, unsigned short* __restrict__ d1, int nb0)
{
    const bool first = (int)blockIdx.x < nb0;
    const float* s = first ? s0 : s1;
    unsigned short* d = first ? d0 : d1;
    const int bid = first ? blockIdx.x : blockIdx.x - nb0;
    const size_t i = ((size_t)bid * 256 + threadIdx.x) * 4;
    float4 v = *(const float4*)&s[i];
    ushort4 u = { f2bf(v.x), f2bf(v.y), f2bf(v.z), f2bf(v.w) };
    *(ushort4*)&d[i] = u;
}

// ---------------------------------------------------------------------------
// K1: V transpose+convert: Vt[b][e][s] bf16 from V[b][s][e] f32.
// ---------------------------------------------------------------------------
__global__ __launch_bounds__(256) void vt_kernel(
    const float* __restrict__ V, unsigned short* __restrict__ Vt)
{
    __shared__ float tile[32][33];
    const int b = blockIdx.z, s0 = blockIdx.x * 32, e0 = blockIdx.y * 32;
    const int t = threadIdx.x;
    const int r = t >> 3, c4 = (t & 7) * 4;
    float4 v = *(const float4*)&V[((size_t)b * S_ + s0 + r) * D_ + e0 + c4];
    tile[r][c4 + 0] = v.x; tile[r][c4 + 1] = v.y;
    tile[r][c4 + 2] = v.z; tile[r][c4 + 3] = v.w;
    __syncthreads();
    ushort4 u;
    u.x = f2bf(tile[c4 + 0][r]); u.y = f2bf(tile[c4 + 1][r]);
    u.z = f2bf(tile[c4 + 2][r]); u.w = f2bf(tile[c4 + 3][r]);
    *(ushort4*)&Vt[((size_t)b * D_ + e0 + r) * S_ + s0 + c4] = u;
}

// ---------------------------------------------------------------------------
// K2: 128xTN-tile bf16 MFMA GEMM, BK=32, double-buffered LDS staged via
// global_load_lds (16B), source-side XOR slot swizzle. 256 thr (4 waves 2x2).
// C = A[M x K] @ Bw[512 x K]^T. grid = 64 * (512/TN), XCD-chunked swizzle.
// MODE 0: P[b][h][s][dk] = bf16((C + bias) * scale)   (QK projection)
// MODE 1: Y = C + bias + Vres (f32)                   (output projection)
// ---------------------------------------------------------------------------
template<int KDIM, int TN, int MODE>
__global__ __launch_bounds__(256) void gemm_t(
    const unsigned short* __restrict__ A, const unsigned short* __restrict__ Bw,
    const float* __restrict__ bias, const float* __restrict__ Vres,
    void* __restrict__ Out, float scale)
{
    constexpr int NB = 512 / TN;       // n-blocks per m-row
    constexpr int CF = TN / 32;        // col frags per wave
    const int o = blockIdx.x;
    const int cpx = gridDim.x / 8;
    const int nb = (o % 8) * cpx + o / 8;   // XCD-chunked bijection
    const int m0 = (nb / NB) * 128;
    const int n0 = (nb % NB) * TN;

    __shared__ __align__(16) unsigned short As[2][128 * 32];
    __shared__ __align__(16) unsigned short Bs[2][TN * 32];

    const int t = threadIdx.x;
    const int wave = t >> 6, lane = t & 63;
    const int wr = wave >> 1, wc = wave & 1;
    const int lr = lane & 15, g = lane >> 4;
    const int gx = (g ^ (lr & 3)) << 3;        // swizzled k-slot (shorts)

    f32x4 acc[4][CF];
    #pragma unroll
    for (int r = 0; r < 4; ++r)
        #pragma unroll
        for (int c = 0; c < CF; ++c) acc[r][c] = (f32x4){0.f, 0.f, 0.f, 0.f};

    const int sub = lane >> 2;                              // row within chunk
    const int cb  = (((lane & 3) ^ (sub & 3)) << 3);        // swizzled src col

    auto stage = [&](int buf, int k0) {
        #pragma unroll
        for (int s = 0; s < 2; ++s) {
            const int chunk = s * 4 + wave;
            const int row = chunk * 16 + sub;
            gload16(&A[(size_t)(m0 + row) * KDIM + k0 + cb], &As[buf][chunk * 512]);
        }
        #pragma unroll
        for (int s = 0; s < TN / 64; ++s) {
            const int chunk = s * 4 + wave;
            const int row = chunk * 16 + sub;
            gload16(&Bw[(size_t)(n0 + row) * KDIM + k0 + cb], &Bs[buf][chunk * 512]);
        }
    };
    auto compute = [&](int cur) {
        bf16x8 af[4], bfr[CF];
        #pragma unroll
        for (int r = 0; r < 4; ++r)
            af[r] = *(const bf16x8*)&As[cur][(wr * 64 + r * 16 + lr) * 32 + gx];
        #pragma unroll
        for (int c = 0; c < CF; ++c)
            bfr[c] = *(const bf16x8*)&Bs[cur][(wc * (TN / 2) + c * 16 + lr) * 32 + gx];
        __builtin_amdgcn_s_setprio(1);
        #pragma unroll
        for (int c = 0; c < CF; ++c)
            #pragma unroll
            for (int r = 0; r < 4; ++r)
                acc[r][c] = __builtin_amdgcn_mfma_f32_16x16x32_bf16(af[r], bfr[c], acc[r][c], 0, 0, 0);
        __builtin_amdgcn_s_setprio(0);
    };

    const int NT = KDIM / 32;
    stage(0, 0);
    __syncthreads();
    int cur = 0;
    for (int tt = 0; tt < NT - 1; ++tt) {
        stage(cur ^ 1, (tt + 1) * 32);   // issue next-tile loads first
        compute(cur);                    // MFMA hides the load latency
        __syncthreads();                 // drain + WAR protect
        cur ^= 1;
    }
    compute(cur);

    float bn[CF];
    #pragma unroll
    for (int c = 0; c < CF; ++c) bn[c] = bias[n0 + wc * (TN / 2) + c * 16 + lr];

    #pragma unroll
    for (int r = 0; r < 4; ++r) {
        #pragma unroll
        for (int c = 0; c < CF; ++c) {
            const int n = n0 + wc * (TN / 2) + c * 16 + lr;
            #pragma unroll
            for (int i = 0; i < 4; ++i) {
                const int m = m0 + wr * 64 + r * 16 + g * 4 + i;
                if constexpr (MODE == 0) {
                    const int srow = m & 1023, bb = m >> 10;
                    const int h = n >> 6, dk = n & 63;
                    ((unsigned short*)Out)[(((size_t)(bb * H_ + h)) * S_ + srow) * DK_ + dk] =
                        f2bf((acc[r][c][i] + bn[c]) * scale);
                } else {
                    const size_t oo = (size_t)m * D_ + n;
                    ((float*)Out)[oo] = acc[r][c][i] + bn[c] + Vres[oo];
                }
            }
        }
    }
}

// ---------------------------------------------------------------------------
// K3: FUSED attention (R6 structure + prefetch/setprio/NT/XCD-swizzle).
// 16 waves (1024 thr), QBLK=64. Swapped QK^T (per-wave k-window 64) -> reg
// softmax -> P bf16 -> swizzled LDS -> NT attn f32 write -> PV MFMA with
// reg-double-buffered V frags -> AV scatter. grid 1024 (1-D, XCD-chunked:
// each XCD owns one batch b -> its Vt/K/Q slices stay L2-hot).
// ---------------------------------------------------------------------------
__global__ __launch_bounds__(1024, 4) void fused_attn(
    const unsigned short* __restrict__ Qbf,   // [B][H][S][64], pre-scaled 0.125
    const unsigned short* __restrict__ Kbf,   // [B][H][S][64]
    const unsigned short* __restrict__ Vt,    // [B][512][1024]
    float* __restrict__ attn,                 // [B][H][S][S]
    unsigned short* __restrict__ AV)          // [B*S][4096]
{
    const int o = blockIdx.x;
    const int nb = (o & 7) * 128 + (o >> 3);   // XCD-chunked bijection (1024=8*128)
    const int bh = nb >> 4;
    const int q0 = (nb & 15) * 64;
    const int b = bh >> 3, h = bh & 7;
    const unsigned short* Qb = Qbf + (size_t)bh * S_ * DK_;
    const unsigned short* Kb = Kbf + (size_t)bh * S_ * DK_;
    const unsigned short* Vb = Vt + (size_t)b * D_ * S_;
    float* outp = attn + ((size_t)bh << 20);

    __shared__ unsigned short PL[64 * 1024];   // 128 KB, swizzled [q][k] bf16
    __shared__ float redm[64][16];
    __shared__ float rowm[64];

    const int t = threadIdx.x;
    const int wave = t >> 6, lane = t & 63;
    const int wcol = wave * 64;     // QK: this wave's k-col window
    const int lr = lane & 15;
    const int g  = lane >> 4;       // 0..3

    // ---- QK^T (swapped): acc[r][c][i] = S[k = wcol+r*16+g*4+i][q = c*16+lr]
    f32x4 acc[4][4];
    #pragma unroll
    for (int r = 0; r < 4; ++r)
        #pragma unroll
        for (int c = 0; c < 4; ++c) acc[r][c] = (f32x4){0.f, 0.f, 0.f, 0.f};

    #pragma unroll
    for (int kk = 0; kk < 2; ++kk) {
        bf16x8 af[4];   // K fragments (A operand, rows = k-cols)
        #pragma unroll
        for (int r = 0; r < 4; ++r)
            af[r] = *(const bf16x8*)&Kb[(size_t)(wcol + r * 16 + lr) * DK_ + kk * 32 + g * 8];
        bf16x8 qf[4];   // Q fragments (B operand, cols = q-rows)
        #pragma unroll
        for (int c = 0; c < 4; ++c)
            qf[c] = *(const bf16x8*)&Qb[(size_t)(q0 + c * 16 + lr) * DK_ + kk * 32 + g * 8];
        __builtin_amdgcn_s_setprio(1);
        #pragma unroll
        for (int r = 0; r < 4; ++r)
            #pragma unroll
            for (int c = 0; c < 4; ++c)
                acc[r][c] = __builtin_amdgcn_mfma_f32_16x16x32_bf16(af[r], qf[c], acc[r][c], 0, 0, 0);
        __builtin_amdgcn_s_setprio(0);
    }

    // ---- softmax stage 1: wave-local max over this wave's 64-k window
    float mloc[4];
    #pragma unroll
    for (int c = 0; c < 4; ++c) {
        float m = acc[0][c][0];
        #pragma unroll
        for (int r = 0; r < 4; ++r)
            #pragma unroll
            for (int i = 0; i < 4; ++i) m = fmaxf(m, acc[r][c][i]);
        m = fmaxf(m, __shfl_xor(m, 16));
        m = fmaxf(m, __shfl_xor(m, 32));
        mloc[c] = m;
    }
    if (lane < 16) {
        #pragma unroll
        for (int c = 0; c < 4; ++c) redm[c * 16 + lane][wave] = mloc[c];
    }
    __syncthreads();
    if (t < 64) {
        float m = redm[t][0];
        #pragma unroll
        for (int w = 1; w < 16; ++w) m = fmaxf(m, redm[t][w]);
        rowm[t] = m;
    }
    __syncthreads();
    // ---- exp + wave-local sum
    float sloc[4];
    #pragma unroll
    for (int c = 0; c < 4; ++c) {
        const float m = rowm[c * 16 + lr];
        float s = 0.f;
        #pragma unroll
        for (int r = 0; r < 4; ++r)
            #pragma unroll
            for (int i = 0; i < 4; ++i) {
                float p = __expf(acc[r][c][i] - m);
                acc[r][c][i] = p;
                s += p;
            }
        s += __shfl_xor(s, 16);
        s += __shfl_xor(s, 32);
        sloc[c] = s;
    }
    __syncthreads();
    if (lane < 16) {
        #pragma unroll
        for (int c = 0; c < 4; ++c) redm[c * 16 + lane][wave] = sloc[c];
    }
    __syncthreads();
    if (t < 64) {
        float s = redm[t][0];
        #pragma unroll
        for (int w = 1; w < 16; ++w) s += redm[t][w];
        rowm[t] = 1.0f / s;
    }
    __syncthreads();

    // ---- normalize; pack P bf16 -> swizzled LDS
    #pragma unroll
    for (int c = 0; c < 4; ++c) {
        const int ql = c * 16 + lr;
        const float ri = rowm[ql];
        #pragma unroll
        for (int r = 0; r < 4; ++r) {
            f32x4 v = acc[r][c];
            v[0] *= ri; v[1] *= ri; v[2] *= ri; v[3] *= ri;
            const int k = wcol + r * 16 + g * 4;
            unsigned p01 = (unsigned)f2bf(v[0]) | ((unsigned)f2bf(v[1]) << 16);
            unsigned p23 = (unsigned)f2bf(v[2]) | ((unsigned)f2bf(v[3]) << 16);
            uint2 pk = { p01, p23 };
            *(uint2*)&PL[plidx(ql, k)] = pk;
        }
    }
    __syncthreads();

    // ---- NT attn f32 write from PL (write-once stream; bypass L2)
    {
        const int arow = t >> 4;          // 0..63
        const int akb  = (t & 15) * 8;    // 0..120
        float* rowp = outp + ((size_t)(q0 + arow) << 10);
        #pragma unroll
        for (int j = 0; j < 8; ++j) {
            const int k = akb + j * 128;
            uint4 u = *(const uint4*)&PL[plidx(arow, k)];
            f32x4 f0, f1;
            f0[0] = __uint_as_float((u.x & 0xffffu) << 16);
            f0[1] = __uint_as_float(u.x & 0xffff0000u);
            f0[2] = __uint_as_float((u.y & 0xffffu) << 16);
            f0[3] = __uint_as_float(u.y & 0xffff0000u);
            f1[0] = __uint_as_float((u.z & 0xffffu) << 16);
            f1[1] = __uint_as_float(u.z & 0xffff0000u);
            f1[2] = __uint_as_float((u.w & 0xffffu) << 16);
            f1[3] = __uint_as_float(u.w & 0xffff0000u);
            __builtin_nontemporal_store(f0, (f32x4*)&rowp[k]);
            __builtin_nontemporal_store(f1, (f32x4*)&rowp[k + 4]);
        }
    }

    // ---- PV: O[q][e]; wave owns e in [wave*32, +32). V frags reg-dbuffered.
    const int we = wave * 32;
    f32x4 accv[4][2];
    #pragma unroll
    for (int r = 0; r < 4; ++r)
        #pragma unroll
        for (int c = 0; c < 2; ++c) accv[r][c] = (f32x4){0.f, 0.f, 0.f, 0.f};

    const unsigned short* vp0 = Vb + (size_t)(we + lr) * S_ + g * 8;
    const unsigned short* vp1 = Vb + (size_t)(we + 16 + lr) * S_ + g * 8;
    bf16x8 vf0 = *(const bf16x8*)vp0;
    bf16x8 vf1 = *(const bf16x8*)vp1;

    for (int k0 = 0; k0 < S_; k0 += 32) {
        bf16x8 nv0, nv1;
        const int kn = k0 + 32;
        if (kn < S_) {                      // prefetch next V frags
            nv0 = *(const bf16x8*)(vp0 + kn);
            nv1 = *(const bf16x8*)(vp1 + kn);
        }
        bf16x8 pa[4];
        #pragma unroll
        for (int r = 0; r < 4; ++r)
            pa[r] = *(const bf16x8*)&PL[plidx(r * 16 + lr, k0 + g * 8)];
        __builtin_amdgcn_s_setprio(1);
        #pragma unroll
        for (int r = 0; r < 4; ++r)
            accv[r][0] = __builtin_amdgcn_mfma_f32_16x16x32_bf16(pa[r], vf0, accv[r][0], 0, 0, 0);
        #pragma unroll
        for (int r = 0; r < 4; ++r)
            accv[r][1] = __builtin_amdgcn_mfma_f32_16x16x32_bf16(pa[r], vf1, accv[r][1], 0, 0, 0);
        __builtin_amdgcn_s_setprio(0);
        if (kn < S_) { vf0 = nv0; vf1 = nv1; }
    }

    // ---- AV scatter store
    #pragma unroll
    for (int r = 0; r < 4; ++r) {
        #pragma unroll
        for (int c = 0; c < 2; ++c) {
            const int e = we + c * 16 + lr;
            #pragma unroll
            for (int i = 0; i < 4; ++i) {
                const int row = q0 + r * 16 + g * 4 + i;
                AV[((size_t)(b * S_ + row)) * HD_ + h * D_ + e] = f2bf(accv[r][c][i]);
            }
        }
    }
}

// ---------------------------------------------------------------------------
// K4: LayerNorm in place. grid 2048, block 256.
// ---------------------------------------------------------------------------
__global__ __launch_bounds__(256) void ln_kernel(
    float* __restrict__ Y, const float* __restrict__ gamma,
    const float* __restrict__ beta)
{
    const int lane = threadIdx.x & 63;
    const int wave = threadIdx.x >> 6;
    const size_t row = (size_t)blockIdx.x * 4 + wave;
    float* p = Y + row * D_;
    float4 v0 = *(float4*)&p[lane * 4];
    float4 v1 = *(float4*)&p[256 + lane * 4];
    float s = v0.x + v0.y + v0.z + v0.w + v1.x + v1.y + v1.z + v1.w;
    float q = v0.x * v0.x + v0.y * v0.y + v0.z * v0.z + v0.w * v0.w +
              v1.x * v1.x + v1.y * v1.y + v1.z * v1.z + v1.w * v1.w;
    #pragma unroll
    for (int m = 1; m < 64; m <<= 1) {
        s += __shfl_xor(s, m);
        q += __shfl_xor(q, m);
    }
    const float mu  = s * (1.f / 512.f);
    const float var = q * (1.f / 512.f) - mu * mu;
    const float r = rsqrtf(var + 1e-5f);
    const float4 g0 = *(const float4*)&gamma[lane * 4];
    const float4 g1 = *(const float4*)&gamma[256 + lane * 4];
    const float4 b0 = *(const float4*)&beta[lane * 4];
    const float4 b1 = *(const float4*)&beta[256 + lane * 4];
    v0.x = (v0.x - mu) * r * g0.x + b0.x;
    v0.y = (v0.y - mu) * r * g0.y + b0.y;
    v0.z = (v0.z - mu) * r * g0.z + b0.z;
    v0.w = (v0.w - mu) * r * g0.w + b0.w;
    v1.x = (v1.x - mu) * r * g1.x + b1.x;
    v1.y = (v1.y - mu) * r * g1.y + b1.y;
    v1.z = (v1.z - mu) * r * g1.z + b1.z;
    v1.w = (v1.w - mu) * r * g1.w + b1.w;
    *(float4*)&p[lane * 4] = v0;
    *(float4*)&p[256 + lane * 4] = v1;
}

// ---------------------------------------------------------------------------
extern "C" void kernel_launch(void* const* d_in, const int* in_sizes, int n_in,
                              void* d_out, int out_size, void* d_ws, size_t ws_size,
                              hipStream_t stream)
{
    const float* query = (const float*)d_in[0];
    const float* key   = (const float*)d_in[1];
    const float* value = (const float*)d_in[2];
    const float* Wq    = (const float*)d_in[3];
    const float* bq    = (const float*)d_in[4];
    const float* Wk    = (const float*)d_in[5];
    const float* bk    = (const float*)d_in[6];
    const float* Wo    = (const float*)d_in[7];
    const float* bo    = (const float*)d_in[8];
    const float* gamma = (const float*)d_in[9];
    const float* beta  = (const float*)d_in[10];

    float* out  = (float*)d_out;                       // [B,S,D] (16 MiB)
    float* attn = out + (size_t)B_ * S_ * D_;          // [B,H,S,S] (256 MiB)
    char*  attnB = (char*)attn;

    char* ws = (char*)d_ws;
    // ws (76 MB): AV [0,64) bf16 ; Vt [64,72) bf16 ; Wobf [72,76) bf16.
    unsigned short* AV   = (unsigned short*)ws;
    unsigned short* Vt   = (unsigned short*)(ws + ((size_t)64 << 20));
    unsigned short* Wobf = (unsigned short*)(ws + ((size_t)72 << 20));
    // Qbf/Kbf (8 MiB each) in the OUT region of d_out (dead before out-GEMM).
    unsigned short* Qbf  = (unsigned short*)d_out;
    unsigned short* Kbf  = (unsigned short*)d_out + ((size_t)4 << 20);  // shorts
    // bf16 copies of X and W in the tail of the ATTN region — consumed by
    // the projections, which complete before fused_attn overwrites attn.
    unsigned short* Xq   = (unsigned short*)(attnB + ((size_t)200 << 20));
    unsigned short* Xk   = (unsigned short*)(attnB + ((size_t)210 << 20));
    unsigned short* Wqbf = (unsigned short*)(attnB + ((size_t)220 << 20));
    unsigned short* Wkbf = (unsigned short*)(attnB + ((size_t)221 << 20));

    cvt2_kernel<<<8192, 256, 0, stream>>>(query, Xq, key, Xk, 4096);
    cvt2_kernel<<<512,  256, 0, stream>>>(Wq, Wqbf, Wk, Wkbf, 256);
    cvt_kernel<<<2048, 256, 0, stream>>>(Wo, Wobf);
    vt_kernel<<<dim3(32, 16, 8), 256, 0, stream>>>(value, Vt);
    gemm_t<512, 64, 0><<<512, 256, 0, stream>>>(Xq, Wqbf, bq, nullptr, (void*)Qbf, 0.125f);
    gemm_t<512, 64, 0><<<512, 256, 0, stream>>>(Xk, Wkbf, bk, nullptr, (void*)Kbf, 1.0f);
    fused_attn<<<1024, 1024, 0, stream>>>(Qbf, Kbf, Vt, attn, AV);
    gemm_t<4096, 64, 1><<<512, 256, 0, stream>>>(AV, Wobf, bo, value, (void*)out, 0.f);
    ln_kernel<<<2048, 256, 0, stream>>>(out, gamma, beta);
}